// Round 8
// baseline (140.586 us; speedup 1.0000x reference)
//
#include <hip/hip_runtime.h>
#include <hip/hip_bf16.h>

// MPNN fused pipeline, R19: two plain dispatches, no cooperative machinery.
// R18 evidence: coop kernel = 164us with ALL pipes idle (MfmaUtil 2.3%,
// VALU 2.9%, HBM 7.6%) -> whole pipeline is latency/sync stall; grid.sync
// is expensive; graph-captured timing ran the fallback (114.7 == R17b).
// Fix:
//  D1  = prep fused into e/G GEMMs: A (X) and B (W) converted fp32->bf16
//        in-kernel during staging (T14 split: load-issue / MFMA / cvt+write).
//        z==0,by==0 blocks also write h[:,0:256]; z==2,by==0 blocks do the
//        Wo0^T -> Bt4[:,0:256] transpose (prep code verbatim).
//        e/G/h bit-identical to R17b (same f2bf inputs, same MFMA k-order).
//  D23 = N split-K GEMM (slab stores, no atomics) + ticket-barrier +
//        convert N->Bt4 + ticket-barrier + final GEMM (R17b mode-0 verbatim).
//        128 blocks, all co-resident (64KB LDS -> 2 blocks/CU cap 512) ->
//        spin-wait is starvation-free. Fences via __hip_atomic AGENT scope.
// Tickets zeroed by D1 (prior dispatch on same stream).

typedef short bf16x8  __attribute__((ext_vector_type(8)));
typedef short short4v __attribute__((ext_vector_type(4)));
typedef float f32x4   __attribute__((ext_vector_type(4)));

__device__ inline short f2bf(float x) {                // fp32 -> bf16 RNE
    unsigned u = __builtin_bit_cast(unsigned, x);
    return (short)((u + 0x7fffu + ((u >> 16) & 1u)) >> 16);
}
__device__ inline float bf2f(short b) {
    return __builtin_bit_cast(float, (unsigned)((unsigned short)b) << 16);
}
__device__ inline void cp16_async(const char* g, char* l) {
    __builtin_amdgcn_global_load_lds(
        (const __attribute__((address_space(1))) unsigned int*)g,
        (__attribute__((address_space(3))) unsigned int*)l, 16, 0, 0);
}

// --------------------------------------------------------------- core128
// 128x128-tile, BK=64, 4 waves 2x2, double-buffered cp16 DMA staging.
// Proven verbatim (R15b/R17b, absmax 0.5).  Ends with __syncthreads().
__device__ __forceinline__ void core128(
    const short* __restrict__ Ap, int lda, const short* __restrict__ Bp, int ldb,
    int kbeg, int kend, int m0, int n0, short* Sf, f32x4 acc[4][4], int t)
{
    const int l = t & 63, lr = l & 15, q = l >> 4;
    const int w = t >> 6, wm = w >> 1, wn = w & 1;
    const int wub = t & ~63;

    auto stage = [&](int buf, int k0) {
        #pragma unroll
        for (int it = 0; it < 4; ++it) {
            int idx = it * 256 + t, r = idx >> 3, s = idx & 7;
            cp16_async((const char*)(Ap + (size_t)(m0 + r) * lda + k0) + s * 16,
                       (char*)(Sf + buf * 16384) + (size_t)(it * 256 + wub) * 16);
        }
        #pragma unroll
        for (int it = 0; it < 4; ++it) {
            int idx = it * 256 + t, r = idx >> 3, s = idx & 7;
            cp16_async((const char*)(Bp + (size_t)(n0 + r) * ldb + k0) + s * 16,
                       (char*)(Sf + buf * 16384 + 8192) + (size_t)(it * 256 + wub) * 16);
        }
    };

    stage(0, kbeg);
    __syncthreads();
    int cur = 0;
    for (int k0 = kbeg; k0 < kend; k0 += 64) {
        if (k0 + 64 < kend) stage(cur ^ 1, k0 + 64);
        const short* As = Sf + cur * 16384;
        const short* Bs = As + 8192;
        #pragma unroll
        for (int ks = 0; ks < 2; ++ks) {
            bf16x8 af[4], bfr[4];
            #pragma unroll
            for (int mt = 0; mt < 4; ++mt) {
                int ar = wm * 64 + mt * 16 + lr;
                af[mt] = *(const bf16x8*)&As[ar * 64 + (((ks*4 + q) ^ (ar & 7)) << 3)];
            }
            #pragma unroll
            for (int nt = 0; nt < 4; ++nt) {
                int br = wn * 64 + nt * 16 + lr;
                bfr[nt] = *(const bf16x8*)&Bs[br * 64 + (((ks*4 + q) ^ (br & 7)) << 3)];
            }
            #pragma unroll
            for (int mt = 0; mt < 4; ++mt)
                #pragma unroll
                for (int nt = 0; nt < 4; ++nt)
                    acc[mt][nt] = __builtin_amdgcn_mfma_f32_16x16x32_bf16(
                        af[mt], bfr[nt], acc[mt][nt], 0, 0, 0);
        }
        __syncthreads();
        cur ^= 1;
    }
}

// ------------------------------------------------------------------ d1_eg
// grid (64,2,4), 256 thr.  z: 0=e1, 1=e2, 2=G1, 3=G2.
// Computes [X bf16] @ [W_z bf16] with in-kernel conversion staging.
// K=256 as 4 steps of BK=64, double-buffered, T14 load/compute/write split.
__global__ __launch_bounds__(256, 1)
void d1_eg(const float* __restrict__ X,
           const float* __restrict__ W1, const float* __restrict__ b1v,
           const float* __restrict__ W2, const float* __restrict__ b2v,
           const float* __restrict__ Wo,
           short* __restrict__ h, short* __restrict__ e1t, short* __restrict__ e2t,
           short* __restrict__ G1t, short* __restrict__ G2t,
           short* __restrict__ Bt4, int* __restrict__ ticket)
{
    const int bx = blockIdx.x, by = blockIdx.y, z = blockIdx.z;
    const int t = threadIdx.x;
    const int l = t & 63, lr = l & 15, q = l >> 4;
    const int w = t >> 6, wm = w >> 1, wn = w & 1;

    if (bx == 0 && by == 0 && z == 0 && t == 0) { ticket[0] = 0; ticket[1] = 0; }

    __shared__ __attribute__((aligned(16))) short S[32768];   // 64 KB

    // ---- side job (64 blocks): Wo0^T -> Bt4[:,0:256], prep code verbatim ----
    if (z == 2 && by == 0) {
        short (*tile)[33] = (short(*)[33])S;
        const int tx = t & 31, ty = t >> 5;
        const int kx = bx >> 3, ny = bx & 7;
        const int dk0 = kx * 32, k0l = kx * 32, n0l = ny * 32;
        #pragma unroll
        for (int i = 0; i < 4; ++i) {
            int row = ty + i * 8;
            tile[row][tx] = f2bf(Wo[(size_t)(k0l + row) * 256 + n0l + tx]);
        }
        __syncthreads();
        #pragma unroll
        for (int i = 0; i < 4; ++i) {
            int row = ty + i * 8;
            int n = n0l + row;
            int slot = ((((dk0 & 32) + tx) >> 3) ^ (n & 7));
            Bt4[(size_t)n * 768 + (dk0 & ~63) + slot * 8 + (tx & 7)] = tile[tx][row];
        }
        __syncthreads();                       // protect S before staging reuse
    }

    const float* Wz   = (z == 0) ? W1 : (z == 1) ? W2 : (Wo + (size_t)(z - 1) * 65536);
    const float* bias = (z == 0) ? b1v : (z == 1) ? b2v : nullptr;
    short* et         = (z == 0) ? e1t : (z == 1) ? e2t : (z == 2) ? G1t : G2t;
    const int  mode   = (z < 2) ? 1 : 3;
    const int  sim    = z & 1;
    const bool writeX = (z == 0 && by == 0);
    const int m0 = bx * 128, n0 = by * 128;

    f32x4 acc[4][4];
    #pragma unroll
    for (int i = 0; i < 4; ++i)
        #pragma unroll
        for (int j = 0; j < 4; ++j) acc[i][j] = f32x4{0.f, 0.f, 0.f, 0.f};

    f32x4 ra[4][2];                            // in-flight A (fp32)
    float rb[4][8];                            // in-flight B (fp32)

    auto loadAB = [&](int k0) {
        #pragma unroll
        for (int i = 0; i < 4; ++i) {          // A: 128 rows x 8 granules
            int idx = i * 256 + t, r = idx >> 3, g = idx & 7;
            const float* xp = X + (size_t)(m0 + r) * 256 + k0 + g * 8;
            ra[i][0] = *(const f32x4*)xp;
            ra[i][1] = *(const f32x4*)(xp + 4);
        }
        #pragma unroll
        for (int i = 0; i < 4; ++i) {          // B: 128 n-rows x 8 granules (transpose)
            int idx = i * 256 + t, n = idx & 127, g = idx >> 7;
            const float* wp = Wz + (size_t)(k0 + g * 8) * 256 + n0 + n;
            #pragma unroll
            for (int j = 0; j < 8; ++j) rb[i][j] = wp[(size_t)j * 256];
        }
    };
    auto writeAB = [&](int buf, int k0) {
        #pragma unroll
        for (int i = 0; i < 4; ++i) {
            int idx = i * 256 + t, r = idx >> 3, g = idx & 7;
            bf16x8 pk;
            pk[0] = f2bf(ra[i][0][0]); pk[1] = f2bf(ra[i][0][1]);
            pk[2] = f2bf(ra[i][0][2]); pk[3] = f2bf(ra[i][0][3]);
            pk[4] = f2bf(ra[i][1][0]); pk[5] = f2bf(ra[i][1][1]);
            pk[6] = f2bf(ra[i][1][2]); pk[7] = f2bf(ra[i][1][3]);
            *(bf16x8*)&S[buf * 16384 + r * 64 + ((g ^ (r & 7)) << 3)] = pk;
            if (writeX)                        // h[:,0:256], swizzled (verbatim layout)
                *(bf16x8*)(h + (size_t)(m0 + r) * 768 + k0 + ((g ^ (r & 7)) << 3)) = pk;
        }
        #pragma unroll
        for (int i = 0; i < 4; ++i) {
            int idx = i * 256 + t, n = idx & 127, g = idx >> 7;
            bf16x8 pk;
            #pragma unroll
            for (int j = 0; j < 8; ++j) pk[j] = f2bf(rb[i][j]);
            *(bf16x8*)&S[buf * 16384 + 8192 + n * 64 + ((g ^ (n & 7)) << 3)] = pk;
        }
    };

    loadAB(0);
    writeAB(0, 0);
    __syncthreads();
    int cur = 0;
    for (int k0 = 0; k0 < 256; k0 += 64) {
        const bool nx = (k0 + 64 < 256);
        if (nx) loadAB(k0 + 64);               // issue loads (latency hides under MFMA)
        const short* As = S + cur * 16384;
        const short* Bs = As + 8192;
        #pragma unroll
        for (int ks = 0; ks < 2; ++ks) {
            bf16x8 af[4], bfr[4];
            #pragma unroll
            for (int mt = 0; mt < 4; ++mt) {
                int ar = wm * 64 + mt * 16 + lr;
                af[mt] = *(const bf16x8*)&As[ar * 64 + (((ks*4 + q) ^ (ar & 7)) << 3)];
            }
            #pragma unroll
            for (int nt = 0; nt < 4; ++nt) {
                int br = wn * 64 + nt * 16 + lr;
                bfr[nt] = *(const bf16x8*)&Bs[br * 64 + (((ks*4 + q) ^ (br & 7)) << 3)];
            }
            #pragma unroll
            for (int mt = 0; mt < 4; ++mt)
                #pragma unroll
                for (int nt = 0; nt < 4; ++nt)
                    acc[mt][nt] = __builtin_amdgcn_mfma_f32_16x16x32_bf16(
                        af[mt], bfr[nt], acc[mt][nt], 0, 0, 0);
        }
        if (nx) writeAB(cur ^ 1, k0 + 64);     // cvt + LDS write after compute
        __syncthreads();
        cur ^= 1;
    }

    // ---- epilogue: R17b mode 1/3 verbatim ----
    short* Hs = S;                             // [128][128]
    short* Ts = S + 16384;                     // [128][128] transposed, swizzled
    #pragma unroll
    for (int mt = 0; mt < 4; ++mt)
        #pragma unroll
        for (int nt = 0; nt < 4; ++nt) {
            int n_loc = wn * 64 + nt * 16 + lr;
            float bb = (mode == 1) ? bias[n0 + n_loc] : 0.f;
            short vb[4];
            #pragma unroll
            for (int r = 0; r < 4; ++r) {
                float v = acc[mt][nt][r] + bb;
                if (mode == 1) v = v > 0.f ? v : 0.f;
                vb[r] = f2bf(v);
                if (mode == 1) {
                    int m_loc = wm * 64 + mt * 16 + q * 4 + r;
                    Hs[m_loc * 128 + n_loc] = vb[r];
                }
            }
            int gm = wm * 8 + mt * 2 + (q >> 1);
            short4v pk = { vb[0], vb[1], vb[2], vb[3] };
            *(short4v*)&Ts[n_loc * 128 + ((gm >> 3) << 6)
                           + (((gm & 7) ^ (n_loc & 7)) << 3) + ((q & 1) << 2)] = pk;
        }
    __syncthreads();
    if (mode == 1) {
        const int cb = 256 + sim * 256 + n0;
        for (int i = t; i < 2048; i += 256) {
            int ml = i >> 4, g = i & 15;
            bf16x8 hv = *(const bf16x8*)&Hs[ml * 128 + g * 8];
            *(bf16x8*)(h + (size_t)(m0 + ml) * 768 + cb + ((g >> 3) << 6)
                       + (((g & 7) ^ (ml & 7)) << 3)) = hv;
        }
    }
    for (int i = t; i < 2048; i += 256) {
        int nl = i >> 4, s = i & 15;
        bf16x8 tv = *(const bf16x8*)&Ts[nl * 128 + s * 8];
        *(bf16x8*)(et + (size_t)(n0 + nl) * 8192 + m0 + s * 8) = tv;
    }
}

// ------------------------------------------------------------------ d23
// grid (128), 256 thr.  All 128 blocks co-resident (64KB LDS -> cap 512).
// Phase N: slab = (G^T e)/256 per (split,sim) quadrant (core128 verbatim).
// Ticket 0 -> convert N (sum 16 slabs) -> Bt4 cols 256:768 (swz, verbatim).
// Ticket 1 -> final GEMM out = relu(h @ Bt4^T + bo) (core128 + mode0 verbatim).
__global__ __launch_bounds__(256, 1)
void d23(const short* __restrict__ e1t, const short* __restrict__ e2t,
         const short* __restrict__ G1t, const short* __restrict__ G2t,
         const short* __restrict__ h, short* __restrict__ Bt4,
         float* __restrict__ Nslab, int* __restrict__ ticket,
         const float* __restrict__ bov, float* __restrict__ outf)
{
    const int fb = blockIdx.x, t = threadIdx.x;
    const int l = t & 63, lr = l & 15, q = l >> 4;
    const int w = t >> 6, wm = w >> 1, wn = w & 1;

    __shared__ __attribute__((aligned(16))) short S[32768];   // 64 KB

    // ---- phase N (R17b job1 mapping: bx=fb&1, by=(fb>>1)&1, bz=fb>>2) ----
    {
        const int bx = fb & 1, by = (fb >> 1) & 1, bz = fb >> 2;
        const int sim = bz & 1, split = bz >> 1;
        const int kbeg = split * 512, m0 = bx * 128, n0 = by * 128;
        const short* Ap = sim ? G2t : G1t;
        const short* Bp = sim ? e2t : e1t;

        f32x4 acc[4][4];
        #pragma unroll
        for (int i = 0; i < 4; ++i)
            #pragma unroll
            for (int j = 0; j < 4; ++j) acc[i][j] = f32x4{0.f, 0.f, 0.f, 0.f};
        core128(Ap, 8192, Bp, 8192, kbeg, kbeg + 512, m0, n0, S, acc, t);

        float* Mo = Nslab + (size_t)(split * 2 + sim) * 65536;
        #pragma unroll
        for (int mt = 0; mt < 4; ++mt)
            #pragma unroll
            for (int nt = 0; nt < 4; ++nt)
                #pragma unroll
                for (int r = 0; r < 4; ++r) {
                    int m = m0 + wm * 64 + mt * 16 + q * 4 + r;
                    int n = n0 + wn * 64 + nt * 16 + lr;
                    Mo[(size_t)m * 256 + n] = acc[mt][nt][r] * (1.0f / 256.0f);
                }
    }

    // ---- ticket 0: all slabs visible ----
    __syncthreads();
    if (t == 0) {
        __threadfence();
        __hip_atomic_fetch_add(&ticket[0], 1, __ATOMIC_ACQ_REL, __HIP_MEMORY_SCOPE_AGENT);
        while (__hip_atomic_load(&ticket[0], __ATOMIC_ACQUIRE, __HIP_MEMORY_SCOPE_AGENT) < 128)
            __builtin_amdgcn_s_sleep(8);
    }
    __syncthreads();
    __threadfence();

    // ---- convert share: granules [fb*128, fb*128+128), t<128 (verbatim math) ----
    if (t < 128) {
        int gid = fb * 128 + t;
        int simg = gid >> 13, rem = gid & 8191;
        int n = rem >> 5, g = rem & 31;
        f32x4 sa = f32x4{0.f, 0.f, 0.f, 0.f}, sb = f32x4{0.f, 0.f, 0.f, 0.f};
        #pragma unroll
        for (int s = 0; s < 16; ++s) {
            const float* np = Nslab + (size_t)(s * 2 + simg) * 65536
                              + (size_t)n * 256 + g * 8;
            sa += *(const f32x4*)np;
            sb += *(const f32x4*)(np + 4);
        }
        bf16x8 pk;
        pk[0] = f2bf(sa[0]); pk[1] = f2bf(sa[1]);
        pk[2] = f2bf(sa[2]); pk[3] = f2bf(sa[3]);
        pk[4] = f2bf(sb[0]); pk[5] = f2bf(sb[1]);
        pk[6] = f2bf(sb[2]); pk[7] = f2bf(sb[3]);
        int k = 256 + simg * 256 + g * 8;
        int slot = (g & 7) ^ (n & 7);
        *(bf16x8*)(Bt4 + (size_t)n * 768 + (k & ~63) + slot * 8) = pk;
    }

    // ---- ticket 1: Bt4 complete ----
    __syncthreads();
    if (t == 0) {
        __threadfence();
        __hip_atomic_fetch_add(&ticket[1], 1, __ATOMIC_ACQ_REL, __HIP_MEMORY_SCOPE_AGENT);
        while (__hip_atomic_load(&ticket[1], __ATOMIC_ACQUIRE, __HIP_MEMORY_SCOPE_AGENT) < 128)
            __builtin_amdgcn_s_sleep(8);
    }
    __syncthreads();
    __threadfence();

    // ---- final GEMM (R17b job2 verbatim): m0=(fb>>1)*128, n0=(fb&1)*128 ----
    {
        const int m0 = (fb >> 1) * 128, n0 = (fb & 1) * 128;
        f32x4 acc[4][4];
        #pragma unroll
        for (int i = 0; i < 4; ++i)
            #pragma unroll
            for (int j = 0; j < 4; ++j) acc[i][j] = f32x4{0.f, 0.f, 0.f, 0.f};
        core128(h, 768, Bt4, 768, 0, 768, m0, n0, S, acc, t);

        #pragma unroll
        for (int mt = 0; mt < 4; ++mt)
            #pragma unroll
            for (int nt = 0; nt < 4; ++nt)
                #pragma unroll
                for (int r = 0; r < 4; ++r) {
                    int m = m0 + wm * 64 + mt * 16 + q * 4 + r;
                    int n = n0 + wn * 64 + nt * 16 + lr;
                    float v = acc[mt][nt][r] + bov[n];
                    outf[(size_t)m * 256 + n] = v > 0.f ? v : 0.f;
                }
    }
}

// ---------------------------------------------------------------- launch
extern "C" void kernel_launch(void* const* d_in, const int* in_sizes, int n_in,
                              void* d_out, int out_size, void* d_ws, size_t ws_size,
                              hipStream_t stream)
{
    const float* edge_x = (const float*)d_in[0];
    const float* W1 = (const float*)d_in[1];
    const float* b1 = (const float*)d_in[2];
    const float* W2 = (const float*)d_in[3];
    const float* b2 = (const float*)d_in[4];
    const float* Wo = (const float*)d_in[5];
    const float* bo = (const float*)d_in[6];

    // workspace (~38.2 MB; poison fill shows ws >= 256 MB)
    char* ws = (char*)d_ws;
    short* h     = (short*)ws;                   // [8192][768] bf16 swz 12,582,912
    short* e1t   = (short*)(ws + 12582912);      // [256][8192] bf16 swz  4,194,304
    short* e2t   = (short*)(ws + 16777216);      // [256][8192] bf16 swz  4,194,304
    short* G1t   = (short*)(ws + 20971520);      // [256][8192] bf16 swz  4,194,304
    short* G2t   = (short*)(ws + 25165824);      // [256][8192] bf16 swz  4,194,304
    short* Bt4   = (short*)(ws + 29360128);      // [256][768]  bf16 swz    393,216
    float* Nslab = (float*)(ws + 29753344);      // [16sp][2sim][256][256] 8,388,608
    int*   tick  = (int*)(ws + 38141952);        // 2 ints

    float* out = (float*)d_out;

    // D1: e1/e2/G1/G2 GEMMs with fused fp32->bf16 conversion staging,
    //     + h[:,0:256] write + Wo0^T side-transpose + ticket zero.
    d1_eg<<<dim3(64, 2, 4), 256, 0, stream>>>(
        edge_x, W1, b1, W2, b2, Wo, h, e1t, e2t, G1t, G2t, Bt4, tick);

    // D23: N slabs -> ticket -> convert -> ticket -> final GEMM.
    d23<<<dim3(128), 256, 0, stream>>>(
        e1t, e2t, G1t, G2t, h, Bt4, Nslab, tick, bo, out);
}